// Round 10
// baseline (306.221 us; speedup 1.0000x reference)
//
#include <hip/hip_runtime.h>

// B=2, C=3, H=W=1024. fp32 in, fp32 out. PASSED R9 @194us: latency-bound
// (VALU 20%, HBM 4%). This round: branchless sampling + both directions
// interleaved + 2 pixels/thread => 4 independent load chains per thread.
// Decision-feeding math (positions, tangent bilinear, vt) stays contract-off
// bit-exact vs the numpy golden — a flipped floor/sign costs O(1) absmax.
constexpr int Bb = 2, Cc = 3, Hh = 1024, Ww = 1024;
constexpr int HWp = Hh * Ww;
constexpr int N_STEPS = 4;
constexpr int PPT = 2;                 // pixels (rows) per thread

struct Corn { int o00, o01, o10, o11; float wx, wy; };

__device__ __forceinline__ Corn mkcorn(float px, float py) {
#pragma clang fp contract(off)
    float fx = px * 1024.0f - 0.5f;    // *1024 exact (pow2); -0.5 rounds once
    float fy = py * 1024.0f - 0.5f;
    float fx0 = floorf(fx), fy0 = floorf(fy);
    Corn c;
    c.wx = fx - fx0;
    c.wy = fy - fy0;
    int x0 = (int)fx0, y0 = (int)fy0;
    int x0i = min(max(x0, 0), Ww - 1);
    int x1i = min(x0i + 1, Ww - 1);
    int y0i = min(max(y0, 0), Hh - 1);
    int y1i = min(y0i + 1, Hh - 1);
    int r0 = y0i * Ww, r1 = y1i * Ww;
    c.o00 = r0 + x0i; c.o01 = r0 + x1i;
    c.o10 = r1 + x0i; c.o11 = r1 + x1i;
    return c;
}

__device__ __forceinline__ float bsamp(const float* __restrict__ p, const Corn& c) {
#pragma clang fp contract(off)
    float v00 = p[c.o00], v01 = p[c.o01], v10 = p[c.o10], v11 = p[c.o11];
    float omx = 1.0f - c.wx, omy = 1.0f - c.wy;
    float top = v00 * omx + v01 * c.wx;
    float bot = v10 * omx + v11 * c.wx;
    return top * omy + bot * c.wy;
}

__global__ __launch_bounds__(256) void flow_smooth_kernel(
    const float* __restrict__ x,
    const float* __restrict__ tg,
    const float* __restrict__ sg,
    float* __restrict__ out)
{
#pragma clang fp contract(off)
    const int j  = blockIdx.x * 64 + threadIdx.x;          // column
    const int i0 = blockIdx.y * (4 * PPT) + threadIdx.y;   // rows i0, i0+4
    const int b  = blockIdx.z;

    const float* xp  = x  + (size_t)b * Cc * HWp;
    const float* txp = tg + (size_t)b * 2 * HWp;
    const float* typ = txp + HWp;

    float sig = sg[b];
    float half_width = 2.0f * sig;
    float two_sigma2 = (2.0f * sig) * sig;
    const float stepf = (float)(1.0 / 0.3333);

    float ks[N_STEPS];
#pragma unroll
    for (int it = 0; it < N_STEPS; ++it) {
        float r = ((float)it + 1.0f) * stepf;
        float k = expf(-(r * r) / two_sigma2);
        ks[it] = (r < half_width) ? k : 0.0f;
    }

    const float inv1024 = 1.0f / 1024.0f;
    const float psx = ((float)j + 0.5f) * inv1024;

    // per-chain state: [pixel][dir]
    int   pix[PPT];
    float px[PPT][2], py[PPT][2], vx[PPT][2], vy[PPT][2];
    float a0[PPT][2], a1[PPT][2], a2[PPT][2], as[PPT][2];

#pragma unroll
    for (int p = 0; p < PPT; ++p) {
        int i = i0 + p * 4;
        pix[p] = i * Ww + j;
        float psy = ((float)i + 0.5f) * inv1024;
        float v0x = txp[pix[p]];
        float v0y = typ[pix[p]];
#pragma unroll
        for (int d = 0; d < 2; ++d) {
            float sxd = d ? -v0x : v0x;
            float syd = d ? -v0y : v0y;
            vx[p][d] = sxd;
            vy[p][d] = syd;
            px[p][d] = psx + sxd * inv1024;   // p0 = p_start + v0/tex
            py[p][d] = psy + syd * inv1024;
            a0[p][d] = 0.f; a1[p][d] = 0.f; a2[p][d] = 0.f; as[p][d] = 0.f;
        }
    }

#pragma unroll
    for (int it = 0; it < N_STEPS; ++it) {
        Corn c[PPT][2];
#pragma unroll
        for (int p = 0; p < PPT; ++p)
#pragma unroll
            for (int d = 0; d < 2; ++d)
                c[p][d] = mkcorn(px[p][d], py[p][d]);

        // tangent samples first (critical path: feeds next position)
        if (it < N_STEPS - 1) {
            float tfx[PPT][2], tfy[PPT][2];
#pragma unroll
            for (int p = 0; p < PPT; ++p)
#pragma unroll
                for (int d = 0; d < 2; ++d) {
                    tfx[p][d] = bsamp(txp, c[p][d]);
                    tfy[p][d] = bsamp(typ, c[p][d]);
                }
            // x samples (non-critical) issued after; weighted branchlessly
#pragma unroll
            for (int p = 0; p < PPT; ++p)
#pragma unroll
                for (int d = 0; d < 2; ++d) {
                    float pxx = px[p][d], pyy = py[p][d];
                    bool inb = (pxx >= 0.0f) && (pxx < 1.0f) &&
                               (pyy >= 0.0f) && (pyy < 1.0f);
                    float w = inb ? ks[it] : 0.0f;    // +0 is a bit-exact no-op
                    a0[p][d] += bsamp(xp, c[p][d]) * w;
                    a1[p][d] += bsamp(xp + HWp, c[p][d]) * w;
                    a2[p][d] += bsamp(xp + 2 * HWp, c[p][d]) * w;
                    as[p][d] += w;
                }
            // advance
#pragma unroll
            for (int p = 0; p < PPT; ++p)
#pragma unroll
                for (int d = 0; d < 2; ++d) {
                    float tx2 = tfx[p][d], ty2 = tfy[p][d];
                    float vt = (vx[p][d] * tx2) + (vy[p][d] * ty2);
                    float sflip = (vt < 0.0f) ? -1.0f : 1.0f;
                    tx2 *= sflip; ty2 *= sflip;       // exact negation
                    px[p][d] = px[p][d] + tx2 * inv1024;
                    py[p][d] = py[p][d] + ty2 * inv1024;
                    vx[p][d] = tx2; vy[p][d] = ty2;
                }
        } else {
            // last step: sample only (ref discards the final advance)
#pragma unroll
            for (int p = 0; p < PPT; ++p)
#pragma unroll
                for (int d = 0; d < 2; ++d) {
                    float pxx = px[p][d], pyy = py[p][d];
                    bool inb = (pxx >= 0.0f) && (pxx < 1.0f) &&
                               (pyy >= 0.0f) && (pyy < 1.0f);
                    float w = inb ? ks[it] : 0.0f;
                    a0[p][d] += bsamp(xp, c[p][d]) * w;
                    a1[p][d] += bsamp(xp + HWp, c[p][d]) * w;
                    a2[p][d] += bsamp(xp + 2 * HWp, c[p][d]) * w;
                    as[p][d] += w;
                }
        }
    }

    float* op = out + (size_t)b * Cc * HWp;
#pragma unroll
    for (int p = 0; p < PPT; ++p) {
        int q = pix[p];
        float xc0 = xp[q], xc1 = xp[q + HWp], xc2 = xp[q + 2 * HWp];
        float denom = (1.0f + as[p][0]) + as[p][1];
        op[q]            = ((xc0 + a0[p][0]) + a0[p][1]) / denom;
        op[q + HWp]      = ((xc1 + a1[p][0]) + a1[p][1]) / denom;
        op[q + 2 * HWp]  = ((xc2 + a2[p][0]) + a2[p][1]) / denom;
    }
}

extern "C" void kernel_launch(void* const* d_in, const int* in_sizes, int n_in,
                              void* d_out, int out_size, void* d_ws, size_t ws_size,
                              hipStream_t stream) {
    const float* x = nullptr; const float* tg = nullptr; const float* sg = nullptr;
    for (int t = 0; t < n_in; ++t) {
        if (in_sizes[t] == Bb * Cc * HWp)      x  = (const float*)d_in[t];
        else if (in_sizes[t] == Bb * 2 * HWp)  tg = (const float*)d_in[t];
        else                                   sg = (const float*)d_in[t];
    }
    float* out = (float*)d_out;

    dim3 block(64, 4, 1);
    dim3 grid(Ww / 64, Hh / (4 * PPT), Bb);
    flow_smooth_kernel<<<grid, block, 0, stream>>>(x, tg, sg, out);
}

// Round 11
// 139.618 us; speedup vs baseline: 2.1933x; 2.1933x over previous
//
#include <hip/hip_runtime.h>

// B=2, C=3, H=W=1024. fp32 in, fp32 out. R9 passed @194us latency-bound
// (VALU 20%, HBM 4%); R10 (2px/thread) regressed by halving TLP (occ 48%).
// R11: LDS-tile all 5 planes (3x + 2 tangent) per 16x16-px block with 6-px
// halo — every gather (within +/-5 px of center) becomes an LDS read; grid
// stays 8192 blocks so TLP stays max. Values pass through LDS unmodified =>
// bit-identical result vs R9 (absmax 0.00390625).
constexpr int Bb = 2, Cc = 3, Hh = 1024, Ww = 1024;
constexpr int HWp = Hh * Ww;
constexpr int N_STEPS = 4;
constexpr int TS = 16;                  // pixels per tile side
constexpr int HALO = 6;                 // >= max drift 4 + ulp, margin 1.9px
constexpr int TD = TS + 2 * HALO;       // 28
constexpr int TSTR = TD + 1;            // 29 (odd stride: breaks bank patterns)

struct Corn { int o00, o01, o10, o11; float wx, wy; };

// positions -> bilinear corners, tile-local LDS offsets. Arithmetic on
// fx/fy/wx/wy is IDENTICAL to the numpy golden (contract off).
__device__ __forceinline__ Corn mkcorn(float px, float py, int ox, int oy) {
#pragma clang fp contract(off)
    float fx = px * 1024.0f - 0.5f;     // *1024 exact (pow2); -0.5 rounds once
    float fy = py * 1024.0f - 0.5f;
    float fx0 = floorf(fx), fy0 = floorf(fy);
    Corn c;
    c.wx = fx - fx0;
    c.wy = fy - fy0;
    int x0 = (int)fx0, y0 = (int)fy0;
    int x0i = min(max(x0, 0), Ww - 1);  // global clamp (border policy)
    int x1i = min(x0i + 1, Ww - 1);
    int y0i = min(max(y0, 0), Hh - 1);
    int y1i = min(y0i + 1, Hh - 1);
    // tile-local; defensive clamp (theoretically always in [0,TD-1])
    int lx0 = min(max(x0i - ox, 0), TD - 1);
    int lx1 = min(max(x1i - ox, 0), TD - 1);
    int ly0 = min(max(y0i - oy, 0), TD - 1);
    int ly1 = min(max(y1i - oy, 0), TD - 1);
    c.o00 = ly0 * TSTR + lx0; c.o01 = ly0 * TSTR + lx1;
    c.o10 = ly1 * TSTR + lx0; c.o11 = ly1 * TSTR + lx1;
    return c;
}

__device__ __forceinline__ float bsamp(const float* p, const Corn& c) {
#pragma clang fp contract(off)
    float v00 = p[c.o00], v01 = p[c.o01], v10 = p[c.o10], v11 = p[c.o11];
    float omx = 1.0f - c.wx, omy = 1.0f - c.wy;
    float top = v00 * omx + v01 * c.wx;
    float bot = v10 * omx + v11 * c.wx;
    return top * omy + bot * c.wy;
}

__global__ __launch_bounds__(256) void flow_smooth_kernel(
    const float* __restrict__ x,
    const float* __restrict__ tg,
    const float* __restrict__ sg,
    float* __restrict__ out)
{
#pragma clang fp contract(off)
    __shared__ float lds[5][TD * TSTR];   // x0,x1,x2,tx,ty : 16.2 KB

    const int tx0 = blockIdx.x * TS, ty0 = blockIdx.y * TS;
    const int b = blockIdx.z;
    const int tid = threadIdx.x;          // 0..255

    const float* xp  = x  + (size_t)b * Cc * HWp;
    const float* txp = tg + (size_t)b * 2 * HWp;
    const float* typ = txp + HWp;
    const float* planes[5] = { xp, xp + HWp, xp + 2 * HWp, txp, typ };

    const int ox = tx0 - HALO, oy = ty0 - HALO;

    // ---- stage 28x28 (border-clamped) x 5 planes into LDS
    for (int e = tid; e < TD * TD; e += 256) {
        int r = e / TD, cc = e - r * TD;
        int gy = min(max(oy + r, 0), Hh - 1);
        int gx = min(max(ox + cc, 0), Ww - 1);
        int g = gy * Ww + gx;
#pragma unroll
        for (int pl = 0; pl < 5; ++pl)
            lds[pl][r * TSTR + cc] = planes[pl][g];
    }
    __syncthreads();

    // ---- per-pixel march (all gathers from LDS)
    const int lx = tid & (TS - 1), ly = tid >> 4;
    const int j = tx0 + lx, i = ty0 + ly;
    const int ctr = (HALO + ly) * TSTR + (HALO + lx);

    float sig = sg[b];
    float half_width = 2.0f * sig;
    float two_sigma2 = (2.0f * sig) * sig;
    const float stepf = (float)(1.0 / 0.3333);

    float ks[N_STEPS];
#pragma unroll
    for (int it = 0; it < N_STEPS; ++it) {
        float r = ((float)it + 1.0f) * stepf;
        float k = expf(-(r * r) / two_sigma2);
        ks[it] = (r < half_width) ? k : 0.0f;
    }

    const float inv1024 = 1.0f / 1024.0f;
    const float psx = ((float)j + 0.5f) * inv1024;
    const float psy = ((float)i + 0.5f) * inv1024;

    float v0x = lds[3][ctr];
    float v0y = lds[4][ctr];

    float c1a = 0.f, c1b = 0.f, c1c = 0.f, s1 = 0.f;
    float c2a = 0.f, c2b = 0.f, c2c = 0.f, s2 = 0.f;

#pragma unroll
    for (int d = 0; d < 2; ++d) {
        float vx = d ? -v0x : v0x;
        float vy = d ? -v0y : v0y;
        float px = psx + vx * inv1024;    // p0 = p_start + v0/tex
        float py = psy + vy * inv1024;
        float a0 = 0.f, a1 = 0.f, a2 = 0.f, as = 0.f;
#pragma unroll
        for (int it = 0; it < N_STEPS; ++it) {
            Corn c = mkcorn(px, py, ox, oy);
            bool inb = (px >= 0.0f) && (px < 1.0f) && (py >= 0.0f) && (py < 1.0f);
            float w = inb ? ks[it] : 0.0f;    // +0 / *0: bit-exact no-op
            a0 += bsamp(lds[0], c) * w;
            a1 += bsamp(lds[1], c) * w;
            a2 += bsamp(lds[2], c) * w;
            as += w;
            if (it == N_STEPS - 1) break;     // ref discards final advance
            float tfx = bsamp(lds[3], c);
            float tfy = bsamp(lds[4], c);
            float vt = (vx * tfx) + (vy * tfy);
            if (vt < 0.0f) { tfx = -tfx; tfy = -tfy; }
            px = px + tfx * inv1024;
            py = py + tfy * inv1024;
            vx = tfx; vy = tfy;
        }
        if (d == 0) { c1a = a0; c1b = a1; c1c = a2; s1 = as; }
        else        { c2a = a0; c2b = a1; c2c = a2; s2 = as; }
    }

    const int pix = i * Ww + j;
    float xc0 = lds[0][ctr], xc1 = lds[1][ctr], xc2 = lds[2][ctr];
    float denom = (1.0f + s1) + s2;
    float* op = out + (size_t)b * Cc * HWp;
    op[pix]           = ((xc0 + c1a) + c2a) / denom;
    op[pix + HWp]     = ((xc1 + c1b) + c2b) / denom;
    op[pix + 2 * HWp] = ((xc2 + c1c) + c2c) / denom;
}

extern "C" void kernel_launch(void* const* d_in, const int* in_sizes, int n_in,
                              void* d_out, int out_size, void* d_ws, size_t ws_size,
                              hipStream_t stream) {
    const float* x = nullptr; const float* tg = nullptr; const float* sg = nullptr;
    for (int t = 0; t < n_in; ++t) {
        if (in_sizes[t] == Bb * Cc * HWp)      x  = (const float*)d_in[t];
        else if (in_sizes[t] == Bb * 2 * HWp)  tg = (const float*)d_in[t];
        else                                   sg = (const float*)d_in[t];
    }
    float* out = (float*)d_out;

    dim3 block(256, 1, 1);
    dim3 grid(Ww / TS, Hh / TS, Bb);   // 64 x 64 x 2 = 8192 blocks
    flow_smooth_kernel<<<grid, block, 0, stream>>>(x, tg, sg, out);
}